// Round 1
// 664.322 us; speedup vs baseline: 1.0342x; 1.0342x over previous
//
#include <hip/hip_runtime.h>

typedef unsigned short u16;
typedef unsigned int   u32;
typedef __attribute__((ext_vector_type(4))) float f32x4;
typedef __attribute__((ext_vector_type(8))) short bf16x8;
typedef __attribute__((ext_vector_type(8))) unsigned short u16x8;

#define MFMA16(a,b,c) __builtin_amdgcn_mfma_f32_16x16x32_bf16(a,b,c,0,0,0)

// head-panel stride: 50176 rows * 48 cols (u16 elements)
#define PANEL 2408448u

__device__ __forceinline__ u16 f32_bf16(float f){
  u32 u = __builtin_bit_cast(u32, f);
  u = (u + 0x7FFFu + ((u >> 16) & 1u)) >> 16;
  return (u16)u;
}

__device__ __forceinline__ void async_cp16(const u16* g, u16* l){
  __builtin_amdgcn_global_load_lds((const __attribute__((address_space(1))) u32*)g,
                                   (__attribute__((address_space(3))) u32*)l, 16, 0, 0);
}

// ---------------------------------------------------------------- cvt x -> bf16
__global__ __launch_bounds__(256)
void cvt_f32_bf16(const float* __restrict__ in, u16* __restrict__ out){
  size_t i = ((size_t)blockIdx.x * 256 + threadIdx.x) * 8;
  f32x4 a = *(const f32x4*)(in + i);
  f32x4 b = *(const f32x4*)(in + i + 4);
  u16x8 o;
  o[0]=f32_bf16(a[0]); o[1]=f32_bf16(a[1]); o[2]=f32_bf16(a[2]); o[3]=f32_bf16(a[3]);
  o[4]=f32_bf16(b[0]); o[5]=f32_bf16(b[1]); o[6]=f32_bf16(b[2]); o[7]=f32_bf16(b[3]);
  *(u16x8*)(out + i) = o;
}

// ------------------------------------------------- transpose+cvt weights (K,N)->(N,K)
__global__ __launch_bounds__(256)
void transpose_cvt(const float* __restrict__ w, u16* __restrict__ wt, int K, int N){
  __shared__ float tile[32][33];
  int n0 = blockIdx.x * 32, k0 = blockIdx.y * 32;
  int tx = threadIdx.x, ty = threadIdx.y;   // 32 x 8
#pragma unroll
  for (int j = 0; j < 32; j += 8) tile[ty + j][tx] = w[(size_t)(k0 + ty + j) * N + n0 + tx];
  __syncthreads();
#pragma unroll
  for (int j = 0; j < 32; j += 8)
    wt[(size_t)(n0 + ty + j) * K + k0 + tx] = f32_bf16(tile[tx][ty + j]);
}

// ------------------------------------------------------------------------------
// 256x256-tile 8-phase bf16 GEMM (T1+T2+T3+T4+T5), BK=64, 8 waves (2M x 4N).
// LDS 128 KiB: double-buffered A[256x64] + B[256x64], XOR-swizzled (conflict-free).
// Counted vmcnt(4) at tile boundaries -- loads stay in flight across barriers.
// ------------------------------------------------------------------------------
template<int A_GATHER>
__device__ __forceinline__ void stage_half(const u16* __restrict__ G, u16* __restrict__ lds,
                                           int tid, int row0, int base, int kt, int ld){
#pragma unroll
  for (int i = 0; i < 2; i++){
    int c = i * 512 + tid;                 // 0..1023 -> 128 rows x 8 k-slots
    int r = c >> 3;
    int kc = (c & 7) ^ (r & 7);            // inverse swizzle on the global source
    const u16* src;
    if (A_GATHER){
      unsigned k0 = (unsigned)(kt + kc * 8);
      unsigned hh = k0 / 48u, dd = k0 - hh * 48u;
      src = G + (size_t)hh * PANEL + (size_t)(base + row0 + r) * 48 + dd;
    } else {
      src = G + (size_t)(base + row0 + r) * ld + kt + kc * 8;
    }
    async_cp16(src, lds + ((size_t)(row0 + r) * 64 + (c & 7) * 8));  // linear dest
  }
}

template<int OUT_BF16, int BIAS, int A_GATHER, int C_HEADS>
__global__ __launch_bounds__(512, 2)
void gemm256(const u16* __restrict__ A, const u16* __restrict__ Bt,
             void* __restrict__ Cv, const float* __restrict__ bias,
             int K, int lda, int ldc, int nbx){
  __shared__ u16 sA[2][256 * 64];
  __shared__ u16 sB[2][256 * 64];
  const int tid  = threadIdx.x;
  const int lane = tid & 63, wave = tid >> 6;
  const int lrow = lane & 15, quad = lane >> 4;
  const int wr = wave >> 2, wc = wave & 3;       // 2 x 4 wave grid

  // T1: bijective XCD-chunked remap (handles nwg % 8 != 0, m204 form)
  const int nwg = (int)gridDim.x;
  const int bid = (int)blockIdx.x;
  const int qq = nwg >> 3, rm = nwg & 7;
  const int xcd = bid & 7, jj = bid >> 3;
  const int f = (xcd < rm ? xcd * (qq + 1) : rm * (qq + 1) + (xcd - rm) * qq) + jj;
  const int bx = f % nbx, by = f / nbx;
  const int m0 = by * 256, n0 = bx * 256;

  const int sw = lrow & 7;
  const int colK0 = (quad ^ sw) * 8;             // kk=0 slot
  const int colK1 = ((4 + quad) ^ sw) * 8;       // kk=1 slot

  f32x4 acc[8][4];
#pragma unroll
  for (int i = 0; i < 8; i++)
#pragma unroll
    for (int j = 0; j < 4; j++) acc[i][j] = (f32x4){0.f, 0.f, 0.f, 0.f};

  const int nt = K >> 6;
  // prologue: tile0 fully + AL/AH(tile1); wait all of tile0 (4 newest stay in flight)
  stage_half<A_GATHER>(A, sA[0], tid, 0,   m0, 0, lda);
  stage_half<A_GATHER>(A, sA[0], tid, 128, m0, 0, lda);
  stage_half<0>(Bt, sB[0], tid, 0,   n0, 0, K);
  stage_half<0>(Bt, sB[0], tid, 128, n0, 0, K);
  stage_half<A_GATHER>(A, sA[1], tid, 0,   m0, 64, lda);
  stage_half<A_GATHER>(A, sA[1], tid, 128, m0, 64, lda);
  asm volatile("s_waitcnt vmcnt(4)" ::: "memory");
  __builtin_amdgcn_s_barrier();

#pragma unroll 1
  for (int t = 0; t < nt; ++t){
    u16* sAb = sA[t & 1];
    u16* sBb = sB[t & 1];
    u16* sBn = sB[(t & 1) ^ 1];
    const int kt1 = (t + 1) << 6, kt2 = (t + 2) << 6;
    bf16x8 A0[8], A1[8], B0[4], B1[4];

    // ---------------- P1: read A[kk0](8) + B[kk0](4); stage BL(t+1)
#pragma unroll
    for (int mi = 0; mi < 8; mi++)
      A0[mi] = *(const bf16x8*)&sAb[(wr * 128 + mi * 16 + lrow) * 64 + colK0];
#pragma unroll
    for (int ni = 0; ni < 4; ni++)
      B0[ni] = *(const bf16x8*)&sBb[(wc * 64 + ni * 16 + lrow) * 64 + colK0];
    if (t + 1 < nt) stage_half<0>(Bt, sBn, tid, 0, n0, kt1, K);
    __builtin_amdgcn_s_barrier();
    asm volatile("s_waitcnt lgkmcnt(0)" ::: "memory");
    __builtin_amdgcn_s_setprio(1);
#pragma unroll
    for (int mi = 0; mi < 8; mi++){
      acc[mi][0] = MFMA16(A0[mi], B0[0], acc[mi][0]);
      acc[mi][1] = MFMA16(A0[mi], B0[1], acc[mi][1]);
    }
    __builtin_amdgcn_s_setprio(0);
    __builtin_amdgcn_s_barrier();

    // ---------------- P2: read A[kk1](8) + B[kk1](4); stage BH(t+1). buffer freed after.
#pragma unroll
    for (int mi = 0; mi < 8; mi++)
      A1[mi] = *(const bf16x8*)&sAb[(wr * 128 + mi * 16 + lrow) * 64 + colK1];
#pragma unroll
    for (int ni = 0; ni < 4; ni++)
      B1[ni] = *(const bf16x8*)&sBb[(wc * 64 + ni * 16 + lrow) * 64 + colK1];
    if (t + 1 < nt) stage_half<0>(Bt, sBn, tid, 128, n0, kt1, K);
    __builtin_amdgcn_s_barrier();
    asm volatile("s_waitcnt lgkmcnt(0)" ::: "memory");
    __builtin_amdgcn_s_setprio(1);
#pragma unroll
    for (int mi = 0; mi < 8; mi++){
      acc[mi][2] = MFMA16(A0[mi], B0[2], acc[mi][2]);
      acc[mi][3] = MFMA16(A0[mi], B0[3], acc[mi][3]);
    }
    __builtin_amdgcn_s_setprio(0);
    __builtin_amdgcn_s_barrier();

    // ---------------- P3: stage AL(t+2) into freed current A buffer
    if (t + 2 < nt) stage_half<A_GATHER>(A, sAb, tid, 0, m0, kt2, lda);
    __builtin_amdgcn_s_barrier();
    __builtin_amdgcn_s_setprio(1);
#pragma unroll
    for (int mi = 0; mi < 8; mi++){
      acc[mi][0] = MFMA16(A1[mi], B1[0], acc[mi][0]);
      acc[mi][1] = MFMA16(A1[mi], B1[1], acc[mi][1]);
    }
    __builtin_amdgcn_s_setprio(0);
    __builtin_amdgcn_s_barrier();

    // ---------------- P4: stage AH(t+2); counted boundary wait
    if (t + 2 < nt) stage_half<A_GATHER>(A, sAb, tid, 128, m0, kt2, lda);
    __builtin_amdgcn_s_barrier();
    __builtin_amdgcn_s_setprio(1);
#pragma unroll
    for (int mi = 0; mi < 8; mi++){
      acc[mi][2] = MFMA16(A1[mi], B1[2], acc[mi][2]);
      acc[mi][3] = MFMA16(A1[mi], B1[3], acc[mi][3]);
    }
    __builtin_amdgcn_s_setprio(0);
    if (t + 2 < nt)      asm volatile("s_waitcnt vmcnt(4)" ::: "memory");
    else if (t + 1 < nt) asm volatile("s_waitcnt vmcnt(0)" ::: "memory");
    __builtin_amdgcn_s_barrier();
  }

  // ---------------- epilogue
#pragma unroll
  for (int mi = 0; mi < 8; mi++){
#pragma unroll
    for (int ni = 0; ni < 4; ni++){
      const int col = n0 + wc * 64 + ni * 16 + lrow;
      if (OUT_BF16 && C_HEADS){
        unsigned which = (unsigned)col / 768u;
        unsigned rem   = (unsigned)col - which * 768u;
        unsigned hh    = rem / 48u;
        unsigned dd    = rem - hh * 48u;
        u16* cb = (u16*)Cv + (size_t)(which * 16u + hh) * PANEL + dd;
#pragma unroll
        for (int r = 0; r < 4; r++){
          int row = m0 + wr * 128 + mi * 16 + quad * 4 + r;
          cb[(size_t)row * 48] = f32_bf16(acc[mi][ni][r]);
        }
      } else {
        float bv = BIAS ? bias[col] : 0.f;
#pragma unroll
        for (int r = 0; r < 4; r++){
          int row = m0 + wr * 128 + mi * 16 + quad * 4 + r;
          float v = acc[mi][ni][r];
          if (OUT_BF16) ((u16*)Cv)[(size_t)row * ldc + col] = f32_bf16(v);
          else          ((float*)Cv)[(size_t)row * ldc + col] = v + bv;
        }
      }
    }
  }
}

// ---------------------------------------- per-(b,h): S=Q K^T (over n), norms, softmax
__global__ __launch_bounds__(256)
void attn_stats(const u16* __restrict__ qkv2, const float* __restrict__ temperature,
                u16* __restrict__ attnb){
  const int h = blockIdx.x, b = blockIdx.y;
  const int tid = threadIdx.x, wave = tid >> 6, lane = tid & 63;
  const int lrow = lane & 15, quad = lane >> 4;
  __shared__ struct {
    union {
      struct { u16 q[48 * 136]; u16 k[48 * 136]; } t;
      float red[2 * 15 * 256];
    } u;
    float S[48 * 49];
    float invq[48], invk[48];
  } sm;

  f32x4 acc[15];
#pragma unroll
  for (int t = 0; t < 15; t++) acc[t] = (f32x4){0.f, 0.f, 0.f, 0.f};

  const u16* qbase = qkv2 + (size_t)h        * PANEL + (size_t)b * 3136 * 48;
  const u16* kbase = qkv2 + (size_t)(16 + h) * PANEL + (size_t)b * 3136 * 48;

  for (int n0 = 0; n0 < 3136; n0 += 128){
    __syncthreads();
#pragma unroll
    for (int i = 0; i < 3; i++){
      int wgrp = i * 4 + wave;
      int qk = wgrp >= 6;
      int dg = qk ? wgrp - 6 : wgrp;
      int n  = n0 + lane * 2;
      const u16* src = (qk ? kbase : qbase) + (size_t)n * 48 + dg * 8;
      u16x8 va = (n     < 3136) ? *(const u16x8*)src        : (u16x8){0,0,0,0,0,0,0,0};
      u16x8 vb = (n + 1 < 3136) ? *(const u16x8*)(src + 48) : (u16x8){0,0,0,0,0,0,0,0};
      u16* dst = qk ? sm.u.t.k : sm.u.t.q;
#pragma unroll
      for (int j = 0; j < 8; j++)
        *(u32*)&dst[(dg * 8 + j) * 136 + lane * 2] = (u32)va[j] | ((u32)vb[j] << 16);
    }
    __syncthreads();
    bf16x8 qf[3], kf[3];
#pragma unroll
    for (int ti = 0; ti < 3; ti++){
      qf[ti] = *(const bf16x8*)&sm.u.t.q[(ti * 16 + lrow) * 136 + wave * 32 + quad * 8];
      kf[ti] = *(const bf16x8*)&sm.u.t.k[(ti * 16 + lrow) * 136 + wave * 32 + quad * 8];
    }
#pragma unroll
    for (int ti = 0; ti < 3; ti++)
#pragma unroll
      for (int tj = 0; tj < 3; tj++)
        acc[ti * 3 + tj] = MFMA16(qf[ti], kf[tj], acc[ti * 3 + tj]);
#pragma unroll
    for (int ti = 0; ti < 3; ti++){
      acc[9  + ti] = MFMA16(qf[ti], qf[ti], acc[9  + ti]);
      acc[12 + ti] = MFMA16(kf[ti], kf[ti], acc[12 + ti]);
    }
  }
  __syncthreads();
  if (wave < 2){
#pragma unroll
    for (int t = 0; t < 15; t++)
      *(f32x4*)&sm.u.red[(wave * 15 + t) * 256 + lane * 4] = acc[t];
  }
  __syncthreads();
  if (wave >= 2){
#pragma unroll
    for (int t = 0; t < 15; t++){
      f32x4* p = (f32x4*)&sm.u.red[((wave - 2) * 15 + t) * 256 + lane * 4];
      *p = *p + acc[t];
    }
  }
  __syncthreads();
  {
    const int p = tid;
    const int lr = p >> 2, r = p & 3;
    const int row16 = ((lr >> 4) << 2) + r, col16 = lr & 15;
#pragma unroll
    for (int t = 0; t < 9; t++){
      float v = sm.u.red[t * 256 + p] + sm.u.red[(15 + t) * 256 + p];
      sm.S[((t / 3) * 16 + row16) * 49 + (t % 3) * 16 + col16] = v;
    }
#pragma unroll
    for (int t = 9; t < 15; t++){
      float v = sm.u.red[t * 256 + p] + sm.u.red[(15 + t) * 256 + p];
      if (row16 == col16){
        if (t < 12) sm.invq[(t - 9)  * 16 + row16] = v;
        else        sm.invk[(t - 12) * 16 + row16] = v;
      }
    }
  }
  __syncthreads();
  if (tid < 96){
    float* arr = (tid < 48) ? sm.invq : sm.invk;
    int d = (tid < 48) ? tid : tid - 48;
    arr[d] = 1.0f / fmaxf(sqrtf(arr[d]), 1e-12f);
  }
  __syncthreads();
  if (tid < 48){
    const int d = tid;
    const float scale = sm.invq[d] * temperature[h];
    float lg[48];
    float mx = -1e30f;
#pragma unroll
    for (int e = 0; e < 48; e++){
      lg[e] = sm.S[d * 49 + e] * scale * sm.invk[e];
      mx = fmaxf(mx, lg[e]);
    }
    float s = 0.f;
#pragma unroll
    for (int e = 0; e < 48; e++){ float ex = __expf(lg[e] - mx); lg[e] = ex; s += ex; }
    const float inv = 1.f / s;
    u16* dst = attnb + ((size_t)(b * 16 + h) * 48 + d) * 64;
#pragma unroll
    for (int e = 0; e < 48; e++) dst[e] = f32_bf16(lg[e] * inv);
#pragma unroll
    for (int e = 48; e < 64; e++) dst[e] = 0;
  }
}

// --------------------------- out_mid[h][m][d] = sum_e attn[b,h,d,e] * v_panel[32+h][m][e]
__global__ __launch_bounds__(256)
void attn_apply_v(const u16* __restrict__ qkv2, const u16* __restrict__ attnb,
                  u16* __restrict__ outm){
  const int h = blockIdx.y, b = blockIdx.z;
  const int nb = blockIdx.x * 256;
  const int tid = threadIdx.x, wave = tid >> 6, lane = tid & 63;
  const int lrow = lane & 15, quad = lane >> 4;
  __shared__ u16 sA[48 * 72];
#pragma unroll
  for (int i = 0; i < 2; i++){
    int idx = i * 256 + tid;
    if (idx < 384){
      int d = idx >> 3, eg = idx & 7;
      *(u16x8*)&sA[d * 72 + eg * 8] =
        *(const u16x8*)&attnb[((size_t)(b * 16 + h) * 48 + d) * 64 + eg * 8];
    }
  }
  __syncthreads();
  bf16x8 bfr[3][2];
#pragma unroll
  for (int tj = 0; tj < 3; tj++){
    bfr[tj][0] = *(const bf16x8*)&sA[(tj * 16 + lrow) * 72 + quad * 8];
    bfr[tj][1] = *(const bf16x8*)&sA[(tj * 16 + lrow) * 72 + 32 + quad * 8];
  }
  f32x4 acc[4][3];
#pragma unroll
  for (int i = 0; i < 4; i++)
#pragma unroll
    for (int j = 0; j < 3; j++) acc[i][j] = (f32x4){0.f, 0.f, 0.f, 0.f};

  const u16* vpanel = qkv2 + (size_t)(32 + h) * PANEL + (size_t)b * 3136 * 48;
  const int eo1 = 32 + ((quad < 2) ? quad * 8 : 0);
#pragma unroll
  for (int mi = 0; mi < 4; mi++){
    int n = nb + wave * 64 + mi * 16 + lrow;
    int nc = n < 3136 ? n : 3135;
    const u16* vp = vpanel + (size_t)nc * 48;
    bf16x8 a0 = *(const bf16x8*)(vp + quad * 8);
    bf16x8 a1 = *(const bf16x8*)(vp + eo1);
#pragma unroll
    for (int tj = 0; tj < 3; tj++){
      acc[mi][tj] = MFMA16(a0, bfr[tj][0], acc[mi][tj]);
      acc[mi][tj] = MFMA16(a1, bfr[tj][1], acc[mi][tj]);
    }
  }
  u16* opanel = outm + (size_t)h * PANEL + (size_t)b * 3136 * 48;
#pragma unroll
  for (int mi = 0; mi < 4; mi++)
#pragma unroll
    for (int tj = 0; tj < 3; tj++){
      int d = tj * 16 + lrow;
#pragma unroll
      for (int r = 0; r < 4; r++){
        int n = nb + wave * 64 + mi * 16 + quad * 4 + r;
        if (n < 3136) opanel[(size_t)n * 48 + d] = f32_bf16(acc[mi][tj][r]);
      }
    }
}

extern "C" void kernel_launch(void* const* d_in, const int* in_sizes, int n_in,
                              void* d_out, int out_size, void* d_ws, size_t ws_size,
                              hipStream_t stream){
  const float* x      = (const float*)d_in[0];   // [16,3136,768]
  const float* qkv_w  = (const float*)d_in[1];   // [768,2304]
  const float* temp   = (const float*)d_in[2];   // [16]
  const float* proj_w = (const float*)d_in[3];   // [768,768]
  const float* proj_b = (const float*)d_in[4];   // [768]
  float* out = (float*)d_out;
  char* ws = (char*)d_ws;

  // workspace layout (bytes)
  const size_t OFF_XB   = 0;            // 50176*768*2   = 77,070,336
  const size_t OFF_WQ   = 77070336;     // 2304*768*2    =  3,538,944
  const size_t OFF_WP   = 80609280;     // 768*768*2     =  1,179,648
  const size_t OFF_QKV  = 81788928;     // 48 panels * 2408448 u16 * 2 = 231,211,008
  const size_t OFF_ATTN = 312999936;    // 16*16*48*64*2 =  1,572,864

  u16* xb    = (u16*)(ws + OFF_XB);
  u16* wqt   = (u16*)(ws + OFF_WQ);
  u16* wpt   = (u16*)(ws + OFF_WP);
  u16* qkv2  = (u16*)(ws + OFF_QKV);   // panels: q 0..15, k 16..31, v 32..47
  u16* attnb = (u16*)(ws + OFF_ATTN);

  // 1) casts / transposes
  cvt_f32_bf16<<<dim3(18816), dim3(256), 0, stream>>>(x, xb);
  transpose_cvt<<<dim3(2304 / 32, 768 / 32), dim3(32, 8), 0, stream>>>(qkv_w, wqt, 768, 2304);
  transpose_cvt<<<dim3(768 / 32, 768 / 32), dim3(32, 8), 0, stream>>>(proj_w, wpt, 768, 768);
  // 2) qkv = x @ qkv_w, scattered to head-major panels (256^2 8-phase, 9x196 tiles)
  gemm256<1, 0, 0, 1><<<dim3(1764), dim3(512), 0, stream>>>(xb, wqt, qkv2, nullptr, 768, 768, 0, 9);
  // 3) per-(b,h) Gram + norms + softmax -> attn [B,H,48,64]
  attn_stats<<<dim3(16, 16), dim3(256), 0, stream>>>(qkv2, temp, attnb);
  // 4) attn @ v -> dead q-panels (0..15) as out_mid [h][m][48]
  attn_apply_v<<<dim3(13, 16, 16), dim3(256), 0, stream>>>(qkv2, attnb, qkv2);
  // 5) out = out_mid @ proj_w + proj_b (fp32 out), A gathered from head panels (3x196 tiles)
  gemm256<0, 1, 1, 0><<<dim3(588), dim3(512), 0, stream>>>(qkv2, wpt, out, proj_b, 768, 0, 768, 3);
}